// Round 2
// baseline (2403.322 us; speedup 1.0000x reference)
//
#include <hip/hip_runtime.h>
#include <math.h>

#define BM 64
#define BN 64
#define BK 16

// modes: 0 = none, 1 = sigmoid, 2 = softplus
__global__ __launch_bounds__(256) void gemm_bias_act(
    const float* __restrict__ A, const float* __restrict__ W,
    const float* __restrict__ bias, float* __restrict__ out,
    int M, int K, int Nc, int mode)
{
    __shared__ float As[BM][BK + 1];
    __shared__ float Ws[BK][BN];

    const int tx = threadIdx.x;
    const int block_row = blockIdx.y * BM;
    const int block_col = blockIdx.x * BN;
    const int tr = tx >> 4;
    const int tc = tx & 15;

    float acc[4][4];
#pragma unroll
    for (int i = 0; i < 4; i++)
#pragma unroll
        for (int j = 0; j < 4; j++) acc[i][j] = 0.f;

    for (int k0 = 0; k0 < K; k0 += BK) {
#pragma unroll
        for (int i = 0; i < 4; i++) {
            int idx = tx + i * 256;
            int r = idx >> 4;
            int kk = idx & 15;
            int gr = block_row + r;
            float v = 0.f;
            if (gr < M) v = A[(size_t)gr * K + k0 + kk];
            As[r][kk] = v;
        }
#pragma unroll
        for (int i = 0; i < 4; i++) {
            int idx = tx + i * 256;
            int kk = idx >> 6;
            int c = idx & 63;
            int gc = block_col + c;
            float v = 0.f;
            if (gc < Nc) v = W[(size_t)(k0 + kk) * Nc + gc];
            Ws[kk][c] = v;
        }
        __syncthreads();

#pragma unroll
        for (int kk = 0; kk < BK; kk++) {
            float a4[4], w4[4];
#pragma unroll
            for (int i = 0; i < 4; i++) a4[i] = As[tr * 4 + i][kk];
#pragma unroll
            for (int j = 0; j < 4; j++) w4[j] = Ws[kk][tc * 4 + j];
#pragma unroll
            for (int i = 0; i < 4; i++)
#pragma unroll
                for (int j = 0; j < 4; j++)
                    acc[i][j] = fmaf(a4[i], w4[j], acc[i][j]);
        }
        __syncthreads();
    }

#pragma unroll
    for (int i = 0; i < 4; i++) {
        int gr = block_row + tr * 4 + i;
        if (gr >= M) continue;
#pragma unroll
        for (int j = 0; j < 4; j++) {
            int gc = block_col + tc * 4 + j;
            if (gc >= Nc) continue;
            float v = acc[i][j] + bias[gc];
            if (mode == 1) {
                v = 1.f / (1.f + __expf(-v));
            } else if (mode == 2) {
                v = (v > 20.f) ? v : log1pf(__expf(v));
            }
            out[(size_t)gr * Nc + gc] = v;
        }
    }
}

// Sequential SSM scan. 16 lanes per (b,d) channel cover the N=16 state dims.
__global__ __launch_bounds__(256) void scan_kernel(
    const float* __restrict__ xs, const float* __restrict__ dt,
    const float* __restrict__ Bm, const float* __restrict__ Cm,
    const float* __restrict__ z, const float* __restrict__ A_log,
    float* __restrict__ y, int L, int D, int N)
{
    const int lane_n = threadIdx.x & 15;
    const int ch = blockIdx.x * 16 + (threadIdx.x >> 4);
    const int b = ch / D;
    const int d = ch % D;

    const float Aval = -expf(A_log[d * N + lane_n]);

    const size_t baseD = (size_t)b * L * D + d;
    const size_t baseN = (size_t)b * L * N + lane_n;

    float h = 0.f;

    float dtv = dt[baseD];
    float xv  = xs[baseD];
    float bv  = Bm[baseN];
    float cv  = Cm[baseN];

    for (int t = 0; t < L; t++) {
        float dtn = 0.f, xvn = 0.f, bvn = 0.f, cvn = 0.f;
        if (t + 1 < L) {
            dtn = dt[baseD + (size_t)(t + 1) * D];
            xvn = xs[baseD + (size_t)(t + 1) * D];
            bvn = Bm[baseN + (size_t)(t + 1) * N];
            cvn = Cm[baseN + (size_t)(t + 1) * N];
        }

        float a = __expf(dtv * Aval);
        h = fmaf(a, h, xv * dtv * bv);
        float contrib = h * cv;
        contrib += __shfl_xor(contrib, 1);
        contrib += __shfl_xor(contrib, 2);
        contrib += __shfl_xor(contrib, 4);
        contrib += __shfl_xor(contrib, 8);
        if (lane_n == 0) {
            y[baseD + (size_t)t * D] = contrib * z[baseD + (size_t)t * D];
        }

        dtv = dtn; xv = xvn; bv = bvn; cv = cvn;
    }
}

extern "C" void kernel_launch(void* const* d_in, const int* in_sizes, int n_in,
                              void* d_out, int out_size, void* d_ws, size_t ws_size,
                              hipStream_t stream) {
    const float* x     = (const float*)d_in[0];
    const float* Wz    = (const float*)d_in[1];
    const float* bz    = (const float*)d_in[2];
    const float* Wx    = (const float*)d_in[3];
    const float* bx    = (const float*)d_in[4];
    const float* WB    = (const float*)d_in[5];
    const float* bB    = (const float*)d_in[6];
    const float* WC    = (const float*)d_in[7];
    const float* bC    = (const float*)d_in[8];
    const float* Wdt   = (const float*)d_in[9];
    const float* bdt   = (const float*)d_in[10];
    const float* A_log = (const float*)d_in[11];
    const float* Wout  = (const float*)d_in[12];
    const float* bout  = (const float*)d_in[13];
    float* out = (float*)d_out;

    const int Bb = 2, L = 2048, D = 1024, N = 16;
    const int M = Bb * L;   // 4096

    float* ws  = (float*)d_ws;
    float* xs  = ws;
    float* dtb = xs  + (size_t)M * D;
    float* yb  = dtb + (size_t)M * D;
    float* Bmb = yb  + (size_t)M * D;
    float* Cmb = Bmb + (size_t)M * N;
    float* zb  = out;   // z staged in d_out; fully overwritten by final GEMM

    dim3 blk(256);
    dim3 gridFull(D / BN, M / BM);   // (16, 64)
    dim3 gridNarrow(1, M / BM);      // Dout = 16

    gemm_bias_act<<<gridFull, blk, 0, stream>>>(x, Wz, bz, zb, M, D, D, 1);
    gemm_bias_act<<<gridFull, blk, 0, stream>>>(x, Wx, bx, xs, M, D, D, 0);
    gemm_bias_act<<<gridFull, blk, 0, stream>>>(x, Wdt, bdt, dtb, M, D, D, 2);
    gemm_bias_act<<<gridNarrow, blk, 0, stream>>>(x, WB, bB, Bmb, M, D, N, 0);
    gemm_bias_act<<<gridNarrow, blk, 0, stream>>>(x, WC, bC, Cmb, M, D, N, 0);

    scan_kernel<<<dim3(Bb * D / 16), blk, 0, stream>>>(xs, dtb, Bmb, Cmb, zb, A_log, yb, L, D, N);

    gemm_bias_act<<<gridFull, blk, 0, stream>>>(yb, Wout, bout, out, M, D, D, 0);
}

// Round 5
// 461.808 us; speedup vs baseline: 5.2042x; 5.2042x over previous
//
#include <hip/hip_runtime.h>
#include <math.h>

// ---------------- narrow f32 GEMM (N=16 projections) ----------------
#define BM 64
#define BN 64
#define BK 16

#define CHUNKS 16
#define LCH    128   // L / CHUNKS

// MFMA GEMM tile
#define TBM 128
#define TBN 64
#define TBK 32
#define LDT 40       // padded LDS row stride in ushorts (80 B, 16B-aligned)

typedef __attribute__((ext_vector_type(8))) short bf16x8;
typedef __attribute__((ext_vector_type(4))) float f32x4;
typedef __attribute__((ext_vector_type(8))) unsigned short us8;
typedef __attribute__((ext_vector_type(4))) unsigned short us4;

__device__ __forceinline__ unsigned short f2bf(float f) {
    unsigned int u = __float_as_uint(f);
    unsigned int r = (u + 0x7FFFu + ((u >> 16) & 1u)) >> 16;   // RNE
    return (unsigned short)r;
}

// modes: 0 = none, 1 = sigmoid, 2 = softplus
__global__ __launch_bounds__(256) void gemm_bias_act(
    const float* __restrict__ A, const float* __restrict__ W,
    const float* __restrict__ bias, float* __restrict__ out,
    int M, int K, int Nc, int mode)
{
    __shared__ float As[BM][BK + 1];
    __shared__ float Ws[BK][BN];

    const int tx = threadIdx.x;
    const int block_row = blockIdx.y * BM;
    const int block_col = blockIdx.x * BN;
    const int tr = tx >> 4;
    const int tc = tx & 15;

    float acc[4][4];
#pragma unroll
    for (int i = 0; i < 4; i++)
#pragma unroll
        for (int j = 0; j < 4; j++) acc[i][j] = 0.f;

    for (int k0 = 0; k0 < K; k0 += BK) {
#pragma unroll
        for (int i = 0; i < 4; i++) {
            int idx = tx + i * 256;
            int r = idx >> 4;
            int kk = idx & 15;
            int gr = block_row + r;
            float v = 0.f;
            if (gr < M) v = A[(size_t)gr * K + k0 + kk];
            As[r][kk] = v;
        }
#pragma unroll
        for (int i = 0; i < 4; i++) {
            int idx = tx + i * 256;
            int kk = idx >> 6;
            int c = idx & 63;
            int gc = block_col + c;
            float v = 0.f;
            if (gc < Nc) v = W[(size_t)(k0 + kk) * Nc + gc];
            Ws[kk][c] = v;
        }
        __syncthreads();

#pragma unroll
        for (int kk = 0; kk < BK; kk++) {
            float a4[4], w4[4];
#pragma unroll
            for (int i = 0; i < 4; i++) a4[i] = As[tr * 4 + i][kk];
#pragma unroll
            for (int j = 0; j < 4; j++) w4[j] = Ws[kk][tc * 4 + j];
#pragma unroll
            for (int i = 0; i < 4; i++)
#pragma unroll
                for (int j = 0; j < 4; j++)
                    acc[i][j] = fmaf(a4[i], w4[j], acc[i][j]);
        }
        __syncthreads();
    }

#pragma unroll
    for (int i = 0; i < 4; i++) {
        int gr = block_row + tr * 4 + i;
        if (gr >= M) continue;
#pragma unroll
        for (int j = 0; j < 4; j++) {
            int gc = block_col + tc * 4 + j;
            if (gc >= Nc) continue;
            float v = acc[i][j] + bias[gc];
            if (mode == 1) {
                v = 1.f / (1.f + __expf(-v));
            } else if (mode == 2) {
                v = (v > 20.f) ? v : log1pf(__expf(v));
            }
            out[(size_t)gr * Nc + gc] = v;
        }
    }
}

// ---------------- conversions ----------------
__global__ __launch_bounds__(256) void convert_bf16(
    const float* __restrict__ in, unsigned short* __restrict__ out, int n4)
{
    int i = blockIdx.x * 256 + threadIdx.x;
    if (i < n4) {
        float4 v = ((const float4*)in)[i];
        us4 u;
        u[0] = f2bf(v.x); u[1] = f2bf(v.y); u[2] = f2bf(v.z); u[3] = f2bf(v.w);
        ((us4*)out)[i] = u;
    }
}

// W[k][n] f32 -> Wt[n][k] bf16, 64x64 tiles via LDS
__global__ __launch_bounds__(256) void transpose_bf16(
    const float* __restrict__ W, unsigned short* __restrict__ Wt, int D)
{
    __shared__ float Ls[64][65];
    const int n0 = blockIdx.x * 64;
    const int k0 = blockIdx.y * 64;
    const int tx = threadIdx.x;

#pragma unroll
    for (int i = 0; i < 4; i++) {
        int idx = tx + i * 256;
        int kr = idx >> 4;
        int ng = idx & 15;
        float4 v = *(const float4*)&W[(size_t)(k0 + kr) * D + n0 + ng * 4];
        Ls[kr][ng * 4 + 0] = v.x;
        Ls[kr][ng * 4 + 1] = v.y;
        Ls[kr][ng * 4 + 2] = v.z;
        Ls[kr][ng * 4 + 3] = v.w;
    }
    __syncthreads();
#pragma unroll
    for (int i = 0; i < 4; i++) {
        int idx = tx + i * 256;
        int nr = idx >> 4;
        int kg = idx & 15;
        us4 u;
#pragma unroll
        for (int j = 0; j < 4; j++) u[j] = f2bf(Ls[kg * 4 + j][nr]);
        *(us4*)&Wt[(size_t)(n0 + nr) * D + k0 + kg * 4] = u;
    }
}

// ---------------- bf16 MFMA GEMM ----------------
// A: [M][K] bf16 row-major; Wt: [Nc][K] bf16 (W transposed); out f32 [M][Nc].
__global__ __launch_bounds__(256) void gemm_mfma(
    const unsigned short* __restrict__ Abf, const unsigned short* __restrict__ Wt,
    const float* __restrict__ bias, float* __restrict__ out,
    int M, int K, int Nc, int mode)
{
    __shared__ unsigned short As[TBM][LDT];
    __shared__ unsigned short Bs[TBN][LDT];

    const int tx = threadIdx.x;
    const int wave = tx >> 6;
    const int lane = tx & 63;
    const int wr = wave >> 1;        // 0..1 : row half (64 rows)
    const int wc = wave & 1;         // 0..1 : col half (32 cols)
    const int lrow = lane & 15;
    const int lk = lane >> 4;        // 0..3
    const int brow = blockIdx.y * TBM;
    const int bcol = blockIdx.x * TBN;

    f32x4 acc[4][2];
#pragma unroll
    for (int m = 0; m < 4; m++)
#pragma unroll
        for (int n = 0; n < 2; n++) acc[m][n] = (f32x4)(0.f);

    for (int k0 = 0; k0 < K; k0 += TBK) {
        // stage A: 128x32 shorts = 512 us8, 2 per thread
#pragma unroll
        for (int i = 0; i < 2; i++) {
            int idx = tx + i * 256;
            int r = idx >> 2;
            int q = idx & 3;
            *(us8*)&As[r][q * 8] =
                *(const us8*)&Abf[(size_t)(brow + r) * K + k0 + q * 8];
        }
        // stage B: 64x32 shorts = 256 us8, 1 per thread
        {
            int c = tx >> 2;
            int q = tx & 3;
            *(us8*)&Bs[c][q * 8] =
                *(const us8*)&Wt[(size_t)(bcol + c) * K + k0 + q * 8];
        }
        __syncthreads();

        bf16x8 av[4], bv[2];
#pragma unroll
        for (int m = 0; m < 4; m++)
            av[m] = *(const bf16x8*)&As[wr * 64 + m * 16 + lrow][lk * 8];
#pragma unroll
        for (int n = 0; n < 2; n++)
            bv[n] = *(const bf16x8*)&Bs[wc * 32 + n * 16 + lrow][lk * 8];
#pragma unroll
        for (int m = 0; m < 4; m++)
#pragma unroll
            for (int n = 0; n < 2; n++)
                acc[m][n] = __builtin_amdgcn_mfma_f32_16x16x32_bf16(
                    av[m], bv[n], acc[m][n], 0, 0, 0);
        __syncthreads();
    }

#pragma unroll
    for (int n = 0; n < 2; n++) {
        int col = bcol + wc * 32 + n * 16 + lrow;
        float bval = bias[col];
#pragma unroll
        for (int m = 0; m < 4; m++) {
#pragma unroll
            for (int r = 0; r < 4; r++) {
                int row = brow + wr * 64 + m * 16 + lk * 4 + r;
                float v = acc[m][n][r] + bval;
                if (mode == 1) {
                    v = 1.f / (1.f + __expf(-v));
                } else if (mode == 2) {
                    v = (v > 20.f) ? v : log1pf(__expf(v));
                }
                out[(size_t)row * Nc + col] = v;
            }
        }
    }
}

// ---------------- chunked scan ----------------
__global__ __launch_bounds__(256) void scan_phase1(
    const float* __restrict__ xs, const float* __restrict__ dt,
    const float* __restrict__ Bm, const float* __restrict__ A_log,
    float* __restrict__ P, float* __restrict__ Hl,
    int L, int D, int N)
{
    const int n  = threadIdx.x & 15;
    const int dl = threadIdx.x >> 4;
    const int d  = blockIdx.x * 16 + dl;
    const int c  = blockIdx.y;
    const int b  = blockIdx.z;

    const float Aval = -expf(A_log[d * N + n]);

    size_t baseD = ((size_t)b * L + (size_t)c * LCH) * D + d;
    size_t baseN = ((size_t)b * L + (size_t)c * LCH) * N + n;

    float h = 0.f, p = 1.f;

    float dtv = dt[baseD];
    float xv  = xs[baseD];
    float bv  = Bm[baseN];

    for (int t = 0; t < LCH; t++) {
        float dtn = 0.f, xvn = 0.f, bvn = 0.f;
        if (t + 1 < LCH) {
            dtn = dt[baseD + (size_t)(t + 1) * D];
            xvn = xs[baseD + (size_t)(t + 1) * D];
            bvn = Bm[baseN + (size_t)(t + 1) * N];
        }
        float a = __expf(dtv * Aval);
        h = fmaf(a, h, xv * dtv * bv);
        p *= a;
        dtv = dtn; xv = xvn; bv = bvn;
    }

    size_t idx = (((size_t)b * D + d) * CHUNKS + c) * N + n;
    P[idx]  = p;
    Hl[idx] = h;
}

__global__ __launch_bounds__(256) void scan_phase2(
    const float* __restrict__ P, float* __restrict__ Hl, int D, int N)
{
    const int tid = blockIdx.x * 256 + threadIdx.x;   // over B*D*N
    const int n = tid & 15;
    const int d = (tid >> 4) & 1023;
    const int b = tid >> 14;

    size_t base = (((size_t)b * D + d) * CHUNKS) * N + n;

    float p[CHUNKS], hl[CHUNKS];
#pragma unroll
    for (int c = 0; c < CHUNKS; c++) {
        p[c]  = P[base + (size_t)c * N];
        hl[c] = Hl[base + (size_t)c * N];
    }
    float run = 0.f;
#pragma unroll
    for (int c = 0; c < CHUNKS; c++) {
        float tmp = hl[c];
        Hl[base + (size_t)c * N] = run;
        run = fmaf(p[c], run, tmp);
    }
}

__global__ __launch_bounds__(256) void scan_phase3(
    const float* __restrict__ xs, const float* __restrict__ dt,
    const float* __restrict__ Bm, const float* __restrict__ Cm,
    const float* __restrict__ z, const float* __restrict__ A_log,
    const float* __restrict__ Hin,
    float* __restrict__ y, int L, int D, int N)
{
    const int n  = threadIdx.x & 15;
    const int dl = threadIdx.x >> 4;
    const int d  = blockIdx.x * 16 + dl;
    const int c  = blockIdx.y;
    const int b  = blockIdx.z;

    const float Aval = -expf(A_log[d * N + n]);

    size_t baseD = ((size_t)b * L + (size_t)c * LCH) * D + d;
    size_t baseN = ((size_t)b * L + (size_t)c * LCH) * N + n;

    float h = Hin[(((size_t)b * D + d) * CHUNKS + c) * N + n];

    float dtv = dt[baseD];
    float xv  = xs[baseD];
    float bv  = Bm[baseN];
    float cv  = Cm[baseN];
    float zv  = z[baseD];

    for (int t = 0; t < LCH; t++) {
        float dtn = 0.f, xvn = 0.f, bvn = 0.f, cvn = 0.f, zvn = 0.f;
        if (t + 1 < LCH) {
            dtn = dt[baseD + (size_t)(t + 1) * D];
            xvn = xs[baseD + (size_t)(t + 1) * D];
            bvn = Bm[baseN + (size_t)(t + 1) * N];
            cvn = Cm[baseN + (size_t)(t + 1) * N];
            zvn = z[baseD + (size_t)(t + 1) * D];
        }
        float a = __expf(dtv * Aval);
        h = fmaf(a, h, xv * dtv * bv);
        float contrib = h * cv;
        contrib += __shfl_xor(contrib, 1);
        contrib += __shfl_xor(contrib, 2);
        contrib += __shfl_xor(contrib, 4);
        contrib += __shfl_xor(contrib, 8);
        if (n == 0) {
            y[baseD + (size_t)t * D] = contrib * zv;
        }
        dtv = dtn; xv = xvn; bv = bvn; cv = cvn; zv = zvn;
    }
}

extern "C" void kernel_launch(void* const* d_in, const int* in_sizes, int n_in,
                              void* d_out, int out_size, void* d_ws, size_t ws_size,
                              hipStream_t stream) {
    const float* x     = (const float*)d_in[0];
    const float* Wz    = (const float*)d_in[1];
    const float* bz    = (const float*)d_in[2];
    const float* Wx    = (const float*)d_in[3];
    const float* bx    = (const float*)d_in[4];
    const float* WB    = (const float*)d_in[5];
    const float* bB    = (const float*)d_in[6];
    const float* WC    = (const float*)d_in[7];
    const float* bC    = (const float*)d_in[8];
    const float* Wdt   = (const float*)d_in[9];
    const float* bdt   = (const float*)d_in[10];
    const float* A_log = (const float*)d_in[11];
    const float* Wout  = (const float*)d_in[12];
    const float* bout  = (const float*)d_in[13];
    float* out = (float*)d_out;

    const int Bb = 2, L = 2048, D = 1024, N = 16;
    const int M = Bb * L;            // 4096
    const size_t MD = (size_t)M * D; // 4M

    float* ws  = (float*)d_ws;
    float* xs  = ws;
    float* dtb = xs  + MD;
    float* yb  = dtb + MD;
    float* Bmb = yb  + MD;
    float* Cmb = Bmb + (size_t)M * N;
    float* Pb  = Cmb + (size_t)M * N;
    float* Hlb = Pb  + (size_t)Bb * D * CHUNKS * N;
    unsigned short* xbf   = (unsigned short*)(Hlb + (size_t)Bb * D * CHUNKS * N);
    unsigned short* Wzt   = xbf + MD;          // xbf reused for y_bf later
    unsigned short* Wxt   = Wzt + (size_t)D * D;
    unsigned short* Wdtt  = Wxt + (size_t)D * D;
    unsigned short* Woutt = Wdtt + (size_t)D * D;
    float* zb = out;   // z staged in d_out; fully overwritten by final GEMM

    dim3 blk(256);
    dim3 gridT(D / 64, D / 64);          // transpose tiles
    dim3 gridMfma(D / TBN, M / TBM);     // (16, 32)
    dim3 gridNarrow(1, M / BM);          // N=16 projections

    // bf16 conversions / transposes
    convert_bf16<<<dim3((unsigned)(MD / 4 / 256)), blk, 0, stream>>>(x, xbf, (int)(MD / 4));
    transpose_bf16<<<gridT, blk, 0, stream>>>(Wz,   Wzt,   D);
    transpose_bf16<<<gridT, blk, 0, stream>>>(Wx,   Wxt,   D);
    transpose_bf16<<<gridT, blk, 0, stream>>>(Wdt,  Wdtt,  D);
    transpose_bf16<<<gridT, blk, 0, stream>>>(Wout, Woutt, D);

    // projections
    gemm_mfma<<<gridMfma, blk, 0, stream>>>(xbf, Wzt,  bz,  zb,  M, D, D, 1);
    gemm_mfma<<<gridMfma, blk, 0, stream>>>(xbf, Wxt,  bx,  xs,  M, D, D, 0);
    gemm_mfma<<<gridMfma, blk, 0, stream>>>(xbf, Wdtt, bdt, dtb, M, D, D, 2);
    gemm_bias_act<<<gridNarrow, blk, 0, stream>>>(x, WB, bB, Bmb, M, D, N, 0);
    gemm_bias_act<<<gridNarrow, blk, 0, stream>>>(x, WC, bC, Cmb, M, D, N, 0);

    // chunked scan
    dim3 gridScan(D / 16, CHUNKS, Bb);
    scan_phase1<<<gridScan, blk, 0, stream>>>(xs, dtb, Bmb, A_log, Pb, Hlb, L, D, N);
    scan_phase2<<<dim3(Bb * D * N / 256), blk, 0, stream>>>(Pb, Hlb, D, N);
    scan_phase3<<<gridScan, blk, 0, stream>>>(xs, dtb, Bmb, Cmb, zb, A_log, Hlb, yb, L, D, N);

    // output projection
    convert_bf16<<<dim3((unsigned)(MD / 4 / 256)), blk, 0, stream>>>(yb, xbf, (int)(MD / 4));
    gemm_mfma<<<gridMfma, blk, 0, stream>>>(xbf, Woutt, bout, out, M, D, D, 0);
}

// Round 7
// 270.120 us; speedup vs baseline: 8.8972x; 1.7096x over previous
//
#include <hip/hip_runtime.h>
#include <math.h>

#define CHUNKS 16
#define LCH    128   // L / CHUNKS

// MFMA GEMM tile
#define TBM 128
#define TBN 64
#define TBK 32
#define LDT 40       // padded LDS row stride in ushorts (80 B, 16B-aligned)

typedef __attribute__((ext_vector_type(8))) short bf16x8;
typedef __attribute__((ext_vector_type(4))) float f32x4;
typedef __attribute__((ext_vector_type(8))) unsigned short us8;
typedef __attribute__((ext_vector_type(4))) unsigned short us4;

__device__ __forceinline__ unsigned short f2bf(float f) {
    unsigned int u = __float_as_uint(f);
    unsigned int r = (u + 0x7FFFu + ((u >> 16) & 1u)) >> 16;   // RNE
    return (unsigned short)r;
}

// ---------------- conversions ----------------
__global__ __launch_bounds__(256) void convert_bf16(
    const float* __restrict__ in, unsigned short* __restrict__ out, int n4)
{
    int i = blockIdx.x * 256 + threadIdx.x;
    if (i < n4) {
        float4 v = ((const float4*)in)[i];
        us4 u;
        u[0] = f2bf(v.x); u[1] = f2bf(v.y); u[2] = f2bf(v.z); u[3] = f2bf(v.w);
        ((us4*)out)[i] = u;
    }
}

// W[k][n] f32 -> Wt[n][k] bf16, 64x64 tiles via LDS
__global__ __launch_bounds__(256) void transpose_bf16(
    const float* __restrict__ W, unsigned short* __restrict__ Wt, int D)
{
    __shared__ float Ls[64][65];
    const int n0 = blockIdx.x * 64;
    const int k0 = blockIdx.y * 64;
    const int tx = threadIdx.x;

#pragma unroll
    for (int i = 0; i < 4; i++) {
        int idx = tx + i * 256;
        int kr = idx >> 4;
        int ng = idx & 15;
        float4 v = *(const float4*)&W[(size_t)(k0 + kr) * D + n0 + ng * 4];
        Ls[kr][ng * 4 + 0] = v.x;
        Ls[kr][ng * 4 + 1] = v.y;
        Ls[kr][ng * 4 + 2] = v.z;
        Ls[kr][ng * 4 + 3] = v.w;
    }
    __syncthreads();
#pragma unroll
    for (int i = 0; i < 4; i++) {
        int idx = tx + i * 256;
        int nr = idx >> 4;
        int kg = idx & 15;
        us4 u;
#pragma unroll
        for (int j = 0; j < 4; j++) u[j] = f2bf(Ls[kg * 4 + j][nr]);
        *(us4*)&Wt[(size_t)(n0 + nr) * D + k0 + kg * 4] = u;
    }
}

// ---------------- bf16 MFMA GEMM ----------------
// A: [M][K] bf16 row-major; Wt: [Nc][K] bf16 (W transposed); out f32 [M][Nc].
__global__ __launch_bounds__(256) void gemm_mfma(
    const unsigned short* __restrict__ Abf, const unsigned short* __restrict__ Wt,
    const float* __restrict__ bias, float* __restrict__ out,
    int M, int K, int Nc, int mode)
{
    __shared__ unsigned short As[TBM][LDT];
    __shared__ unsigned short Bs[TBN][LDT];

    const int tx = threadIdx.x;
    const int wave = tx >> 6;
    const int lane = tx & 63;
    const int wr = wave >> 1;        // 0..1 : row half (64 rows)
    const int wc = wave & 1;         // 0..1 : col half (32 cols)
    const int lrow = lane & 15;
    const int lk = lane >> 4;        // 0..3
    const int brow = blockIdx.y * TBM;
    const int bcol = blockIdx.x * TBN;

    f32x4 acc[4][2];
#pragma unroll
    for (int m = 0; m < 4; m++)
#pragma unroll
        for (int n = 0; n < 2; n++) acc[m][n] = (f32x4)(0.f);

    for (int k0 = 0; k0 < K; k0 += TBK) {
        // stage A: 128x32 shorts = 512 us8, 2 per thread
#pragma unroll
        for (int i = 0; i < 2; i++) {
            int idx = tx + i * 256;
            int r = idx >> 2;
            int q = idx & 3;
            *(us8*)&As[r][q * 8] =
                *(const us8*)&Abf[(size_t)(brow + r) * K + k0 + q * 8];
        }
        // stage B: 64x32 shorts = 256 us8, 1 per thread
        {
            int c = tx >> 2;
            int q = tx & 3;
            *(us8*)&Bs[c][q * 8] =
                *(const us8*)&Wt[(size_t)(bcol + c) * K + k0 + q * 8];
        }
        __syncthreads();

        bf16x8 av[4], bv[2];
#pragma unroll
        for (int m = 0; m < 4; m++)
            av[m] = *(const bf16x8*)&As[wr * 64 + m * 16 + lrow][lk * 8];
#pragma unroll
        for (int n = 0; n < 2; n++)
            bv[n] = *(const bf16x8*)&Bs[wc * 32 + n * 16 + lrow][lk * 8];
#pragma unroll
        for (int m = 0; m < 4; m++)
#pragma unroll
            for (int n = 0; n < 2; n++)
                acc[m][n] = __builtin_amdgcn_mfma_f32_16x16x32_bf16(
                    av[m], bv[n], acc[m][n], 0, 0, 0);
        __syncthreads();
    }

#pragma unroll
    for (int n = 0; n < 2; n++) {
        int col = bcol + wc * 32 + n * 16 + lrow;
        float bval = bias[col];
#pragma unroll
        for (int m = 0; m < 4; m++) {
#pragma unroll
            for (int r = 0; r < 4; r++) {
                int row = brow + wr * 64 + m * 16 + lk * 4 + r;
                float v = acc[m][n][r] + bval;
                if (mode == 1) {
                    v = 1.f / (1.f + __expf(-v));
                } else if (mode == 2) {
                    v = (v > 20.f) ? v : log1pf(__expf(v));
                }
                out[(size_t)row * Nc + col] = v;
            }
        }
    }
}

// ---------------- fused B+C projection ----------------
// out: Bm[M][16], Cm[M][16].  Weights staged as bf16 [32][1024] in LDS with a
// 16B-granule XOR swizzle (k ^ ((n&15)<<3)) -> <=2-way bank aliasing (free).
// Each thread owns one (row, output) pair: n = tx&31 (0..15 -> Bm, 16..31 -> Cm),
// r = tx>>5 (8 rows/block). x loads are wave-broadcast float4s.
__global__ __launch_bounds__(256) void bc_proj(
    const float* __restrict__ x,
    const float* __restrict__ WB, const float* __restrict__ bB,
    const float* __restrict__ WC, const float* __restrict__ bC,
    float* __restrict__ Bm, float* __restrict__ Cm, int K)
{
    __shared__ unsigned short Wl[32 * 1024];   // 64 KB

    const int tx = threadIdx.x;

    // stage WB (16384 f32 = 4096 float4, 16/thread) into rows 0..15
#pragma unroll
    for (int i = 0; i < 16; i++) {
        int e = tx + i * 256;
        int k = e >> 2;
        int n0 = (e & 3) * 4;
        float4 v = ((const float4*)WB)[e];
        float vv[4] = {v.x, v.y, v.z, v.w};
#pragma unroll
        for (int j = 0; j < 4; j++) {
            int n = n0 + j;
            Wl[n * 1024 + (((k & ~7) ^ ((n & 15) << 3)) | (k & 7))] = f2bf(vv[j]);
        }
    }
    // stage WC into rows 16..31
#pragma unroll
    for (int i = 0; i < 16; i++) {
        int e = tx + i * 256;
        int k = e >> 2;
        int n0 = (e & 3) * 4;
        float4 v = ((const float4*)WC)[e];
        float vv[4] = {v.x, v.y, v.z, v.w};
#pragma unroll
        for (int j = 0; j < 4; j++) {
            int n = 16 + n0 + j;
            Wl[n * 1024 + (((k & ~7) ^ ((n & 15) << 3)) | (k & 7))] = f2bf(vv[j]);
        }
    }
    __syncthreads();

    const int n = tx & 31;
    const int r = tx >> 5;
    const int row = blockIdx.x * 8 + r;

    const unsigned short* wrow = &Wl[n * 1024];
    const int sw = (n & 15) << 3;
    const float* xrow = &x[(size_t)row * K];

    float acc = 0.f;
    for (int kb = 0; kb < K; kb += 8) {
        us8 w8 = *(const us8*)&wrow[kb ^ sw];
        float4 xa = *(const float4*)&xrow[kb];
        float4 xb = *(const float4*)&xrow[kb + 4];
        float xv[8] = {xa.x, xa.y, xa.z, xa.w, xb.x, xb.y, xb.z, xb.w};
#pragma unroll
        for (int j = 0; j < 8; j++) {
            acc = fmaf(xv[j], __uint_as_float((unsigned)(unsigned short)w8[j] << 16), acc);
        }
    }

    if (n < 16) Bm[(size_t)row * 16 + n] = acc + bB[n];
    else        Cm[(size_t)row * 16 + (n - 16)] = acc + bC[n - 16];
}

// ---------------- chunked scan ----------------
__global__ __launch_bounds__(256) void scan_phase1(
    const float* __restrict__ xs, const float* __restrict__ dt,
    const float* __restrict__ Bm, const float* __restrict__ A_log,
    float* __restrict__ P, float* __restrict__ Hl,
    int L, int D, int N)
{
    const int n  = threadIdx.x & 15;
    const int dl = threadIdx.x >> 4;
    const int d  = blockIdx.x * 16 + dl;
    const int c  = blockIdx.y;
    const int b  = blockIdx.z;

    const float Aval = -expf(A_log[d * N + n]);

    size_t baseD = ((size_t)b * L + (size_t)c * LCH) * D + d;
    size_t baseN = ((size_t)b * L + (size_t)c * LCH) * N + n;

    float h = 0.f, p = 1.f;

    float dtv = dt[baseD];
    float xv  = xs[baseD];
    float bv  = Bm[baseN];

    for (int t = 0; t < LCH; t++) {
        float dtn = 0.f, xvn = 0.f, bvn = 0.f;
        if (t + 1 < LCH) {
            dtn = dt[baseD + (size_t)(t + 1) * D];
            xvn = xs[baseD + (size_t)(t + 1) * D];
            bvn = Bm[baseN + (size_t)(t + 1) * N];
        }
        float a = __expf(dtv * Aval);
        h = fmaf(a, h, xv * dtv * bv);
        p *= a;
        dtv = dtn; xv = xvn; bv = bvn;
    }

    size_t idx = (((size_t)b * D + d) * CHUNKS + c) * N + n;
    P[idx]  = p;
    Hl[idx] = h;
}

__global__ __launch_bounds__(256) void scan_phase2(
    const float* __restrict__ P, float* __restrict__ Hl, int D, int N)
{
    const int tid = blockIdx.x * 256 + threadIdx.x;   // over B*D*N
    const int n = tid & 15;
    const int d = (tid >> 4) & 1023;
    const int b = tid >> 14;

    size_t base = (((size_t)b * D + d) * CHUNKS) * N + n;

    float p[CHUNKS], hl[CHUNKS];
#pragma unroll
    for (int c = 0; c < CHUNKS; c++) {
        p[c]  = P[base + (size_t)c * N];
        hl[c] = Hl[base + (size_t)c * N];
    }
    float run = 0.f;
#pragma unroll
    for (int c = 0; c < CHUNKS; c++) {
        float tmp = hl[c];
        Hl[base + (size_t)c * N] = run;
        run = fmaf(p[c], run, tmp);
    }
}

__global__ __launch_bounds__(256) void scan_phase3(
    const float* __restrict__ xs, const float* __restrict__ dt,
    const float* __restrict__ Bm, const float* __restrict__ Cm,
    const float* __restrict__ z, const float* __restrict__ A_log,
    const float* __restrict__ Hin,
    float* __restrict__ y, int L, int D, int N)
{
    const int n  = threadIdx.x & 15;
    const int dl = threadIdx.x >> 4;
    const int d  = blockIdx.x * 16 + dl;
    const int c  = blockIdx.y;
    const int b  = blockIdx.z;

    const float Aval = -expf(A_log[d * N + n]);

    size_t baseD = ((size_t)b * L + (size_t)c * LCH) * D + d;
    size_t baseN = ((size_t)b * L + (size_t)c * LCH) * N + n;

    float h = Hin[(((size_t)b * D + d) * CHUNKS + c) * N + n];

    float dtv = dt[baseD];
    float xv  = xs[baseD];
    float bv  = Bm[baseN];
    float cv  = Cm[baseN];
    float zv  = z[baseD];

    for (int t = 0; t < LCH; t++) {
        float dtn = 0.f, xvn = 0.f, bvn = 0.f, cvn = 0.f, zvn = 0.f;
        if (t + 1 < LCH) {
            dtn = dt[baseD + (size_t)(t + 1) * D];
            xvn = xs[baseD + (size_t)(t + 1) * D];
            bvn = Bm[baseN + (size_t)(t + 1) * N];
            cvn = Cm[baseN + (size_t)(t + 1) * N];
            zvn = z[baseD + (size_t)(t + 1) * D];
        }
        float a = __expf(dtv * Aval);
        h = fmaf(a, h, xv * dtv * bv);
        float contrib = h * cv;
        contrib += __shfl_xor(contrib, 1);
        contrib += __shfl_xor(contrib, 2);
        contrib += __shfl_xor(contrib, 4);
        contrib += __shfl_xor(contrib, 8);
        if (n == 0) {
            y[baseD + (size_t)t * D] = contrib * zv;
        }
        dtv = dtn; xv = xvn; bv = bvn; cv = cvn; zv = zvn;
    }
}

extern "C" void kernel_launch(void* const* d_in, const int* in_sizes, int n_in,
                              void* d_out, int out_size, void* d_ws, size_t ws_size,
                              hipStream_t stream) {
    const float* x     = (const float*)d_in[0];
    const float* Wz    = (const float*)d_in[1];
    const float* bz    = (const float*)d_in[2];
    const float* Wx    = (const float*)d_in[3];
    const float* bx    = (const float*)d_in[4];
    const float* WB    = (const float*)d_in[5];
    const float* bB    = (const float*)d_in[6];
    const float* WC    = (const float*)d_in[7];
    const float* bC    = (const float*)d_in[8];
    const float* Wdt   = (const float*)d_in[9];
    const float* bdt   = (const float*)d_in[10];
    const float* A_log = (const float*)d_in[11];
    const float* Wout  = (const float*)d_in[12];
    const float* bout  = (const float*)d_in[13];
    float* out = (float*)d_out;

    const int Bb = 2, L = 2048, D = 1024, N = 16;
    const int M = Bb * L;            // 4096
    const size_t MD = (size_t)M * D; // 4M

    float* ws  = (float*)d_ws;
    float* xs  = ws;
    float* dtb = xs  + MD;
    float* yb  = dtb + MD;
    float* Bmb = yb  + MD;
    float* Cmb = Bmb + (size_t)M * N;
    float* Pb  = Cmb + (size_t)M * N;
    float* Hlb = Pb  + (size_t)Bb * D * CHUNKS * N;
    unsigned short* xbf   = (unsigned short*)(Hlb + (size_t)Bb * D * CHUNKS * N);
    unsigned short* Wzt   = xbf + MD;          // xbf reused for y_bf later
    unsigned short* Wxt   = Wzt + (size_t)D * D;
    unsigned short* Wdtt  = Wxt + (size_t)D * D;
    unsigned short* Woutt = Wdtt + (size_t)D * D;
    float* zb = out;   // z staged in d_out; fully overwritten by final GEMM

    dim3 blk(256);
    dim3 gridT(D / 64, D / 64);          // transpose tiles
    dim3 gridMfma(D / TBN, M / TBM);     // (16, 32)

    // bf16 conversions / transposes
    convert_bf16<<<dim3((unsigned)(MD / 4 / 256)), blk, 0, stream>>>(x, xbf, (int)(MD / 4));
    transpose_bf16<<<gridT, blk, 0, stream>>>(Wz,   Wzt,   D);
    transpose_bf16<<<gridT, blk, 0, stream>>>(Wx,   Wxt,   D);
    transpose_bf16<<<gridT, blk, 0, stream>>>(Wdt,  Wdtt,  D);
    transpose_bf16<<<gridT, blk, 0, stream>>>(Wout, Woutt, D);

    // projections
    gemm_mfma<<<gridMfma, blk, 0, stream>>>(xbf, Wzt,  bz,  zb,  M, D, D, 1);
    gemm_mfma<<<gridMfma, blk, 0, stream>>>(xbf, Wxt,  bx,  xs,  M, D, D, 0);
    gemm_mfma<<<gridMfma, blk, 0, stream>>>(xbf, Wdtt, bdt, dtb, M, D, D, 2);
    bc_proj<<<dim3(M / 8), blk, 0, stream>>>(x, WB, bB, WC, bC, Bmb, Cmb, D);

    // chunked scan
    dim3 gridScan(D / 16, CHUNKS, Bb);
    scan_phase1<<<gridScan, blk, 0, stream>>>(xs, dtb, Bmb, A_log, Pb, Hlb, L, D, N);
    scan_phase2<<<dim3(Bb * D * N / 256), blk, 0, stream>>>(Pb, Hlb, D, N);
    scan_phase3<<<gridScan, blk, 0, stream>>>(xs, dtb, Bmb, Cmb, zb, A_log, Hlb, yb, L, D, N);

    // output projection
    convert_bf16<<<dim3((unsigned)(MD / 4 / 256)), blk, 0, stream>>>(yb, xbf, (int)(MD / 4));
    gemm_mfma<<<gridMfma, blk, 0, stream>>>(xbf, Woutt, bout, out, M, D, D, 0);
}